// Round 1
// baseline (487.669 us; speedup 1.0000x reference)
//
#include <hip/hip_runtime.h>
#include <math.h>

#define B_ 8
#define C_ 256
#define N_ 4096          // H*W = 64*64
#define NPOS 32768       // B*N
#define SCALE_ 0.1767766952966369f   // 32^-0.5
#define EPS_ 1e-5f

// ---------------- kernel 1: sub + layernorm over channels ----------------
// block = 256 threads handles 32 spatial positions (half a row) x 256 channels
__global__ __launch_bounds__(256) void k_sub_ln(
    const float* __restrict__ vi, const float* __restrict__ ir,
    const float* __restrict__ ln_g, const float* __restrict__ ln_b,
    float* __restrict__ sub, float* __restrict__ xn)
{
  __shared__ float tile[C_ * 33];          // [c][x] stride 33
  __shared__ float redS[8][32], redS2[8][32];
  __shared__ float meanS[32], rstdS[32];
  int blk = blockIdx.x;                    // b*128 + y*2 + half
  int b = blk >> 7;
  int y = (blk >> 1) & 63;
  int half = blk & 1;
  int t = threadIdx.x;
  size_t base = (size_t)b * C_ * N_ + (size_t)y * 64 + half * 32;
  #pragma unroll 4
  for (int it = 0; it < 32; ++it) {
    int c = it * 8 + (t >> 5);
    int x = t & 31;
    size_t g = base + (size_t)c * N_ + x;
    float s = vi[g] - ir[g];
    sub[g] = s;
    tile[c * 33 + x] = s;
  }
  __syncthreads();
  {
    int p = t & 31, grp = t >> 5;
    float s = 0.f, s2 = 0.f;
    #pragma unroll
    for (int cc = 0; cc < 32; ++cc) {
      float v = tile[(grp * 32 + cc) * 33 + p];
      s += v; s2 += v * v;
    }
    redS[grp][p] = s; redS2[grp][p] = s2;
  }
  __syncthreads();
  if (t < 32) {
    float s = 0.f, s2 = 0.f;
    #pragma unroll
    for (int g2 = 0; g2 < 8; ++g2) { s += redS[g2][t]; s2 += redS2[g2][t]; }
    float mu = s * (1.f / 256.f);
    float var = s2 * (1.f / 256.f) - mu * mu;
    meanS[t] = mu;
    rstdS[t] = rsqrtf(var + EPS_);
  }
  __syncthreads();
  int c = t;
  float gg = ln_g[c], bb = ln_b[c];
  size_t xbase = ((size_t)b * N_ + (size_t)y * 64 + half * 32) * C_;
  for (int p = 0; p < 32; ++p) {
    float v = (tile[c * 33 + p] - meanS[p]) * rstdS[p] * gg + bb;
    xn[xbase + (size_t)p * C_ + c] = v;   // position-major [NPOS, 256]
  }
}

// ---------------- kernel 2: qkv GEMM  C[M,768] = A[M,256] * B[768,256]^T ----
__global__ __launch_bounds__(256) void k_gemm_qkv(
    const float* __restrict__ A, const float* __restrict__ Bw,
    float* __restrict__ C)
{
  __shared__ float As[16][68];
  __shared__ float Bs[16][68];
  int tid = threadIdx.x;
  int tx = tid & 15, ty = tid >> 4;
  int m0 = blockIdx.x * 64;
  int n0 = blockIdx.y * 64;
  int lm = tid >> 2;
  int lk = (tid & 3) << 2;
  float acc[4][4] = {};
  const float* Aptr = A + (size_t)(m0 + lm) * 256 + lk;
  const float* Bptr = Bw + (size_t)(n0 + lm) * 256 + lk;
  for (int k0 = 0; k0 < 256; k0 += 16) {
    float4 av = *(const float4*)(Aptr + k0);
    float4 bv = *(const float4*)(Bptr + k0);
    As[lk + 0][lm] = av.x; As[lk + 1][lm] = av.y; As[lk + 2][lm] = av.z; As[lk + 3][lm] = av.w;
    Bs[lk + 0][lm] = bv.x; Bs[lk + 1][lm] = bv.y; Bs[lk + 2][lm] = bv.z; Bs[lk + 3][lm] = bv.w;
    __syncthreads();
    #pragma unroll
    for (int kk = 0; kk < 16; ++kk) {
      float4 a = *(const float4*)&As[kk][ty << 2];
      float4 b = *(const float4*)&Bs[kk][tx << 2];
      acc[0][0] += a.x * b.x; acc[0][1] += a.x * b.y; acc[0][2] += a.x * b.z; acc[0][3] += a.x * b.w;
      acc[1][0] += a.y * b.x; acc[1][1] += a.y * b.y; acc[1][2] += a.y * b.z; acc[1][3] += a.y * b.w;
      acc[2][0] += a.z * b.x; acc[2][1] += a.z * b.y; acc[2][2] += a.z * b.z; acc[2][3] += a.z * b.w;
      acc[3][0] += a.w * b.x; acc[3][1] += a.w * b.y; acc[3][2] += a.w * b.z; acc[3][3] += a.w * b.w;
    }
    __syncthreads();
  }
  #pragma unroll
  for (int i = 0; i < 4; ++i) {
    float4 w = make_float4(acc[i][0], acc[i][1], acc[i][2], acc[i][3]);
    *(float4*)&C[(size_t)(m0 + (ty << 2) + i) * 768 + n0 + (tx << 2)] = w;
  }
}

// ---------------- kernel 3: dilated local attention ----------------
// one 32-lane group per (position, dil-group, head); 8 items per block = one position
__global__ __launch_bounds__(256) void k_attn(
    const float* __restrict__ qkv,   // [NPOS, 768]
    float* __restrict__ y)           // [NPOS, 256]
{
  int t = threadIdx.x;
  int item = blockIdx.x * 8 + (t >> 5);
  int lane = t & 31;
  int ih = item & 7;          // i*2 + h
  int p = item >> 3;
  int i = ih >> 1, h = ih & 1;
  int dil = i + 1;            // DIL = (1,2,3,4)
  int b = p >> 12;
  int n = p & 4095;
  int py = n >> 6, px = n & 63;
  int off = i * 64 + h * 32 + lane;
  float q = qkv[(size_t)p * 768 + off];
  float sc[9];
  #pragma unroll
  for (int j = 0; j < 9; ++j) {
    int ny = py + (j / 3 - 1) * dil;
    int nx = px + (j % 3 - 1) * dil;
    bool inb = ((unsigned)ny < 64u) && ((unsigned)nx < 64u);
    int pj = (b << 12) + (ny << 6) + nx;
    float kv = inb ? qkv[(size_t)pj * 768 + 256 + off] : 0.f;
    float s = q * kv;
    #pragma unroll
    for (int m = 16; m; m >>= 1) s += __shfl_xor(s, m, 32);
    sc[j] = s * SCALE_;       // zero-padded taps contribute score 0 (NOT -inf)
  }
  float mx = sc[0];
  #pragma unroll
  for (int j = 1; j < 9; ++j) mx = fmaxf(mx, sc[j]);
  float e[9], sum = 0.f;
  #pragma unroll
  for (int j = 0; j < 9; ++j) { e[j] = expf(sc[j] - mx); sum += e[j]; }
  float inv = 1.f / sum;
  float out = 0.f;
  #pragma unroll
  for (int j = 0; j < 9; ++j) {
    int ny = py + (j / 3 - 1) * dil;
    int nx = px + (j % 3 - 1) * dil;
    bool inb = ((unsigned)ny < 64u) && ((unsigned)nx < 64u);
    int pj = (b << 12) + (ny << 6) + nx;
    float vv = inb ? qkv[(size_t)pj * 768 + 512 + off] : 0.f;
    out += (e[j] * inv) * vv;
  }
  y[(size_t)p * 256 + off] = out;
}

// ---------------- kernel 4: proj GEMM + bias + residual, scatter to BCHW ----
__global__ __launch_bounds__(256) void k_gemm_proj(
    const float* __restrict__ A,    // y [NPOS,256]
    const float* __restrict__ Bw,   // proj_w [256,256]
    const float* __restrict__ bias,
    const float* __restrict__ sub,  // BCHW
    float* __restrict__ divm)       // BCHW
{
  __shared__ float As[16][68];
  __shared__ float Bs[16][68];
  int tid = threadIdx.x;
  int tx = tid & 15, ty = tid >> 4;
  int m0 = blockIdx.x * 64;
  int n0 = blockIdx.y * 64;
  int lm = tid >> 2;
  int lk = (tid & 3) << 2;
  float acc[4][4] = {};
  const float* Aptr = A + (size_t)(m0 + lm) * 256 + lk;
  const float* Bptr = Bw + (size_t)(n0 + lm) * 256 + lk;
  for (int k0 = 0; k0 < 256; k0 += 16) {
    float4 av = *(const float4*)(Aptr + k0);
    float4 bv = *(const float4*)(Bptr + k0);
    As[lk + 0][lm] = av.x; As[lk + 1][lm] = av.y; As[lk + 2][lm] = av.z; As[lk + 3][lm] = av.w;
    Bs[lk + 0][lm] = bv.x; Bs[lk + 1][lm] = bv.y; Bs[lk + 2][lm] = bv.z; Bs[lk + 3][lm] = bv.w;
    __syncthreads();
    #pragma unroll
    for (int kk = 0; kk < 16; ++kk) {
      float4 a = *(const float4*)&As[kk][ty << 2];
      float4 b = *(const float4*)&Bs[kk][tx << 2];
      acc[0][0] += a.x * b.x; acc[0][1] += a.x * b.y; acc[0][2] += a.x * b.z; acc[0][3] += a.x * b.w;
      acc[1][0] += a.y * b.x; acc[1][1] += a.y * b.y; acc[1][2] += a.y * b.z; acc[1][3] += a.y * b.w;
      acc[2][0] += a.z * b.x; acc[2][1] += a.z * b.y; acc[2][2] += a.z * b.z; acc[2][3] += a.z * b.w;
      acc[3][0] += a.w * b.x; acc[3][1] += a.w * b.y; acc[3][2] += a.w * b.z; acc[3][3] += a.w * b.w;
    }
    __syncthreads();
  }
  int b = m0 >> 12;
  #pragma unroll
  for (int i = 0; i < 4; ++i) {
    int p = m0 + (ty << 2) + i;
    int n = p & 4095;
    #pragma unroll
    for (int j = 0; j < 4; ++j) {
      int c = n0 + (tx << 2) + j;
      size_t idx = ((size_t)(b * 256 + c)) * 4096 + n;
      divm[idx] = sub[idx] + bias[c] + acc[i][j];
    }
  }
}

// ---------------- kernel 5: per-(b,c) 64x64x64 matmul, dup output ----------
__global__ __launch_bounds__(256) void k_bmm(
    const float* __restrict__ vi, const float* __restrict__ divm,
    float* __restrict__ out)
{
  __shared__ float At[64 * 68];   // transposed A: At[k][i]
  __shared__ float Bsm[64 * 64];  // B row-major [k][j]
  int bc = blockIdx.x;
  size_t base = (size_t)bc * 4096;
  int t = threadIdx.x;
  #pragma unroll
  for (int it = 0; it < 4; ++it) {
    int flat = it * 1024 + t * 4;
    int row = flat >> 6, col = flat & 63;
    float4 a = *(const float4*)&vi[base + flat];
    float4 bv = *(const float4*)&divm[base + flat];
    At[(col + 0) * 68 + row] = a.x;
    At[(col + 1) * 68 + row] = a.y;
    At[(col + 2) * 68 + row] = a.z;
    At[(col + 3) * 68 + row] = a.w;
    *(float4*)&Bsm[flat] = bv;
  }
  __syncthreads();
  int tx = t & 15, ty = t >> 4;
  float acc[4][4] = {};
  for (int k = 0; k < 64; ++k) {
    float4 a = *(const float4*)&At[k * 68 + (ty << 2)];
    float4 b = *(const float4*)&Bsm[k * 64 + (tx << 2)];
    acc[0][0] += a.x * b.x; acc[0][1] += a.x * b.y; acc[0][2] += a.x * b.z; acc[0][3] += a.x * b.w;
    acc[1][0] += a.y * b.x; acc[1][1] += a.y * b.y; acc[1][2] += a.y * b.z; acc[1][3] += a.y * b.w;
    acc[2][0] += a.z * b.x; acc[2][1] += a.z * b.y; acc[2][2] += a.z * b.z; acc[2][3] += a.z * b.w;
    acc[3][0] += a.w * b.x; acc[3][1] += a.w * b.y; acc[3][2] += a.w * b.z; acc[3][3] += a.w * b.w;
  }
  #pragma unroll
  for (int i = 0; i < 4; ++i) {
    int row = (ty << 2) + i;
    float4 w = make_float4(acc[i][0], acc[i][1], acc[i][2], acc[i][3]);
    *(float4*)&out[base + row * 64 + (tx << 2)] = w;
    *(float4*)&out[8388608ull + base + row * 64 + (tx << 2)] = w;
  }
}

extern "C" void kernel_launch(void* const* d_in, const int* in_sizes, int n_in,
                              void* d_out, int out_size, void* d_ws, size_t ws_size,
                              hipStream_t stream) {
  const float* vi     = (const float*)d_in[0];
  const float* ir     = (const float*)d_in[1];
  const float* w_qkv  = (const float*)d_in[2];
  const float* proj_w = (const float*)d_in[3];
  const float* proj_b = (const float*)d_in[4];
  const float* ln_g   = (const float*)d_in[5];
  const float* ln_b   = (const float*)d_in[6];
  float* out = (float*)d_out;
  char* ws = (char*)d_ws;
  float* sub = (float*)(ws);                  // 33.5 MB  [B,C,H,W]
  float* xn  = (float*)(ws + 33554432);       // 33.5 MB  [NPOS,256]
  float* qkv = (float*)(ws + 67108864);       // 100.7 MB [NPOS,768]
  float* yb   = xn;    // reuse after qkv GEMM consumes xn
  float* divm = qkv;   // reuse after attention consumes qkv

  k_sub_ln<<<1024, 256, 0, stream>>>(vi, ir, ln_g, ln_b, sub, xn);
  k_gemm_qkv<<<dim3(512, 12), 256, 0, stream>>>(xn, w_qkv, qkv);
  k_attn<<<32768, 256, 0, stream>>>(qkv, yb);
  k_gemm_proj<<<dim3(512, 4), 256, 0, stream>>>(yb, proj_w, proj_b, sub, divm);
  k_bmm<<<2048, 256, 0, stream>>>(vi, divm, out);
}

// Round 2
// 324.089 us; speedup vs baseline: 1.5047x; 1.5047x over previous
//
#include <hip/hip_runtime.h>
#include <math.h>

#define B_ 8
#define C_ 256
#define N_ 4096          // H*W
#define NPOS 32768       // B*N
#define SCALE_ 0.1767766952966369f
#define EPS_ 1e-5f

typedef __attribute__((ext_vector_type(8))) short bf16x8;
typedef __attribute__((ext_vector_type(4))) float f32x4;

__device__ __forceinline__ unsigned short f2bf(float f) {
  union { float f; unsigned u; } v; v.f = f;
  unsigned r = v.u + 0x7fff + ((v.u >> 16) & 1);   // RNE
  return (unsigned short)(r >> 16);
}
__device__ __forceinline__ float bf2f(unsigned short u) {
  union { unsigned u; float f; } v; v.u = ((unsigned)u) << 16; return v.f;
}

#define GLD_LDS16(g, l) \
  __builtin_amdgcn_global_load_lds((const __attribute__((address_space(1))) unsigned int*)(g), \
                                   (__attribute__((address_space(3))) unsigned int*)(l), 16, 0, 0)

// ---------------- kernel 0: convert weights to bf16 ----------------
// w_qkv: 196608 floats, proj_w: 65536 floats -> contiguous bf16 dst
__global__ __launch_bounds__(256) void k_cvt(
    const float* __restrict__ wq, const float* __restrict__ pw,
    unsigned short* __restrict__ dst)
{
  int i4 = blockIdx.x * 256 + threadIdx.x;          // 65536 float4s total
  float4 v = (i4 < 49152) ? ((const float4*)wq)[i4] : ((const float4*)pw)[i4 - 49152];
  ushort4 o;
  o.x = f2bf(v.x); o.y = f2bf(v.y); o.z = f2bf(v.z); o.w = f2bf(v.w);
  ((ushort4*)dst)[i4] = o;
}

// ---------------- kernel 1: sub + layernorm, bf16 xn ----------------
__global__ __launch_bounds__(256) void k_sub_ln(
    const float* __restrict__ vi, const float* __restrict__ ir,
    const float* __restrict__ ln_g, const float* __restrict__ ln_b,
    float* __restrict__ sub, unsigned short* __restrict__ xn)
{
  __shared__ float tile[C_ * 33];
  __shared__ float redS[8][32], redS2[8][32];
  __shared__ float meanS[32], rstdS[32];
  int blk = blockIdx.x;
  int b = blk >> 7;
  int y = (blk >> 1) & 63;
  int half = blk & 1;
  int t = threadIdx.x;
  size_t base = (size_t)b * C_ * N_ + (size_t)y * 64 + half * 32;
  #pragma unroll 4
  for (int it = 0; it < 32; ++it) {
    int c = it * 8 + (t >> 5);
    int x = t & 31;
    size_t g = base + (size_t)c * N_ + x;
    float s = vi[g] - ir[g];
    sub[g] = s;
    tile[c * 33 + x] = s;
  }
  __syncthreads();
  {
    int p = t & 31, grp = t >> 5;
    float s = 0.f, s2 = 0.f;
    #pragma unroll
    for (int cc = 0; cc < 32; ++cc) {
      float v = tile[(grp * 32 + cc) * 33 + p];
      s += v; s2 += v * v;
    }
    redS[grp][p] = s; redS2[grp][p] = s2;
  }
  __syncthreads();
  if (t < 32) {
    float s = 0.f, s2 = 0.f;
    #pragma unroll
    for (int g2 = 0; g2 < 8; ++g2) { s += redS[g2][t]; s2 += redS2[g2][t]; }
    float mu = s * (1.f / 256.f);
    float var = s2 * (1.f / 256.f) - mu * mu;
    meanS[t] = mu;
    rstdS[t] = rsqrtf(var + EPS_);
  }
  __syncthreads();
  int c = t;
  float gg = ln_g[c], bb = ln_b[c];
  size_t xbase = ((size_t)b * N_ + (size_t)y * 64 + half * 32) * C_;
  for (int p = 0; p < 32; ++p) {
    float v = (tile[c * 33 + p] - meanS[p]) * rstdS[p] * gg + bb;
    xn[xbase + (size_t)p * C_ + c] = f2bf(v);
  }
}

// ---------------- MFMA GEMM: C[M,N] = A[M,256] * B[N,256]^T ----------------
// 128x128 tile, 4 waves (2x2), each wave 64x64 via 4x4 mfma_16x16x32 tiles.
// EPI 0: store bf16 C at ldc stride. EPI 1: proj epilogue (bias + residual,
// scatter fp32 to BCHW).
template<int EPI>
__global__ __launch_bounds__(256) void k_gemm_mfma(
    const unsigned short* __restrict__ A,
    const unsigned short* __restrict__ Bw,
    void* __restrict__ Cout,
    const float* __restrict__ bias,
    const float* __restrict__ sub,
    int ldc)
{
  __shared__ __align__(16) unsigned short As[128 * 32];
  __shared__ __align__(16) unsigned short Bs[128 * 32];
  int tid = threadIdx.x;
  int wv = tid >> 6;
  int lane = tid & 63;
  int m0 = blockIdx.x * 128;
  int n0 = blockIdx.y * 128;
  int mw = (wv >> 1) * 64, nw = (wv & 1) * 64;
  int r = lane & 15, q = lane >> 4;

  // staging: wave wv loads rows [32*wv, 32*wv+32) of both tiles;
  // two 1KB segments per tile, lane l -> 16B at seg_base + 16*l
  int seg0 = wv * 2;
  int srow0 = seg0 * 16 + (lane >> 2);
  int scol = (lane & 3) * 8;
  const unsigned short* ga0 = A  + (size_t)(m0 + srow0) * 256 + scol;
  const unsigned short* ga1 = ga0 + 16 * 256;
  const unsigned short* gb0 = Bw + (size_t)(n0 + srow0) * 256 + scol;
  const unsigned short* gb1 = gb0 + 16 * 256;
  unsigned short* la0 = &As[seg0 * 512];
  unsigned short* la1 = la0 + 512;
  unsigned short* lb0 = &Bs[seg0 * 512];
  unsigned short* lb1 = lb0 + 512;

  f32x4 acc[4][4];
  #pragma unroll
  for (int i = 0; i < 4; ++i)
    #pragma unroll
    for (int j = 0; j < 4; ++j)
      acc[i][j] = (f32x4){0.f, 0.f, 0.f, 0.f};

  for (int k0 = 0; k0 < 256; k0 += 32) {
    GLD_LDS16(ga0 + k0, la0);
    GLD_LDS16(ga1 + k0, la1);
    GLD_LDS16(gb0 + k0, lb0);
    GLD_LDS16(gb1 + k0, lb1);
    __syncthreads();
    bf16x8 af[4], bfr[4];
    #pragma unroll
    for (int mt = 0; mt < 4; ++mt)
      af[mt] = *(const bf16x8*)&As[(mw + mt * 16 + r) * 32 + q * 8];
    #pragma unroll
    for (int nt = 0; nt < 4; ++nt)
      bfr[nt] = *(const bf16x8*)&Bs[(nw + nt * 16 + r) * 32 + q * 8];
    #pragma unroll
    for (int mt = 0; mt < 4; ++mt)
      #pragma unroll
      for (int nt = 0; nt < 4; ++nt)
        acc[mt][nt] = __builtin_amdgcn_mfma_f32_16x16x32_bf16(af[mt], bfr[nt], acc[mt][nt], 0, 0, 0);
    __syncthreads();
  }

  if (EPI == 0) {
    unsigned short* C = (unsigned short*)Cout;
    #pragma unroll
    for (int mt = 0; mt < 4; ++mt)
      #pragma unroll
      for (int nt = 0; nt < 4; ++nt) {
        int n = n0 + nw + nt * 16 + r;
        #pragma unroll
        for (int rr = 0; rr < 4; ++rr) {
          int m = m0 + mw + mt * 16 + q * 4 + rr;
          C[(size_t)m * ldc + n] = f2bf(acc[mt][nt][rr]);
        }
      }
  } else {
    float* divm = (float*)Cout;
    #pragma unroll
    for (int mt = 0; mt < 4; ++mt) {
      int p0 = m0 + mw + mt * 16 + q * 4;
      int b = p0 >> 12, nn = p0 & 4095;
      #pragma unroll
      for (int nt = 0; nt < 4; ++nt) {
        int c = n0 + nw + nt * 16 + r;
        size_t idx = ((size_t)(b * 256 + c)) * 4096 + nn;
        float4 s4 = *(const float4*)&sub[idx];
        float bb = bias[c];
        float4 o;
        o.x = s4.x + bb + acc[mt][nt][0];
        o.y = s4.y + bb + acc[mt][nt][1];
        o.z = s4.z + bb + acc[mt][nt][2];
        o.w = s4.w + bb + acc[mt][nt][3];
        *(float4*)&divm[idx] = o;
      }
    }
  }
}

// ---------------- kernel 3: dilated local attention (bf16 qkv/y) ----------
__global__ __launch_bounds__(256) void k_attn(
    const unsigned short* __restrict__ qkv,   // [NPOS, 768] bf16
    unsigned short* __restrict__ y)           // [NPOS, 256] bf16
{
  int t = threadIdx.x;
  int item = blockIdx.x * 8 + (t >> 5);
  int lane = t & 31;
  int ih = item & 7;
  int p = item >> 3;
  int i = ih >> 1, h = ih & 1;
  int dil = i + 1;
  int b = p >> 12;
  int n = p & 4095;
  int py = n >> 6, px = n & 63;
  int off = i * 64 + h * 32 + lane;
  float qv = bf2f(qkv[(size_t)p * 768 + off]);
  float sc[9];
  #pragma unroll
  for (int j = 0; j < 9; ++j) {
    int ny = py + (j / 3 - 1) * dil;
    int nx = px + (j % 3 - 1) * dil;
    bool inb = ((unsigned)ny < 64u) && ((unsigned)nx < 64u);
    int pj = (b << 12) + (ny << 6) + nx;
    float kv = inb ? bf2f(qkv[(size_t)pj * 768 + 256 + off]) : 0.f;
    float s = qv * kv;
    #pragma unroll
    for (int m = 16; m; m >>= 1) s += __shfl_xor(s, m, 32);
    sc[j] = s * SCALE_;       // zero-padded taps give score 0 (NOT -inf)
  }
  float mx = sc[0];
  #pragma unroll
  for (int j = 1; j < 9; ++j) mx = fmaxf(mx, sc[j]);
  float e[9], sum = 0.f;
  #pragma unroll
  for (int j = 0; j < 9; ++j) { e[j] = expf(sc[j] - mx); sum += e[j]; }
  float inv = 1.f / sum;
  float out = 0.f;
  #pragma unroll
  for (int j = 0; j < 9; ++j) {
    int ny = py + (j / 3 - 1) * dil;
    int nx = px + (j % 3 - 1) * dil;
    bool inb = ((unsigned)ny < 64u) && ((unsigned)nx < 64u);
    int pj = (b << 12) + (ny << 6) + nx;
    float vv = inb ? bf2f(qkv[(size_t)pj * 768 + 512 + off]) : 0.f;
    out += (e[j] * inv) * vv;
  }
  y[(size_t)p * 256 + off] = f2bf(out);
}

// ---------------- kernel 5: per-(b,c) 64x64x64 matmul, dup output ----------
__global__ __launch_bounds__(256) void k_bmm(
    const float* __restrict__ vi, const float* __restrict__ divm,
    float* __restrict__ out)
{
  __shared__ float At[64 * 68];
  __shared__ float Bsm[64 * 64];
  int bc = blockIdx.x;
  size_t base = (size_t)bc * 4096;
  int t = threadIdx.x;
  #pragma unroll
  for (int it = 0; it < 4; ++it) {
    int flat = it * 1024 + t * 4;
    int row = flat >> 6, col = flat & 63;
    float4 a = *(const float4*)&vi[base + flat];
    float4 bv = *(const float4*)&divm[base + flat];
    At[(col + 0) * 68 + row] = a.x;
    At[(col + 1) * 68 + row] = a.y;
    At[(col + 2) * 68 + row] = a.z;
    At[(col + 3) * 68 + row] = a.w;
    *(float4*)&Bsm[flat] = bv;
  }
  __syncthreads();
  int tx = t & 15, ty = t >> 4;
  float acc[4][4] = {};
  for (int k = 0; k < 64; ++k) {
    float4 a = *(const float4*)&At[k * 68 + (ty << 2)];
    float4 b = *(const float4*)&Bsm[k * 64 + (tx << 2)];
    acc[0][0] += a.x * b.x; acc[0][1] += a.x * b.y; acc[0][2] += a.x * b.z; acc[0][3] += a.x * b.w;
    acc[1][0] += a.y * b.x; acc[1][1] += a.y * b.y; acc[1][2] += a.y * b.z; acc[1][3] += a.y * b.w;
    acc[2][0] += a.z * b.x; acc[2][1] += a.z * b.y; acc[2][2] += a.z * b.z; acc[2][3] += a.z * b.w;
    acc[3][0] += a.w * b.x; acc[3][1] += a.w * b.y; acc[3][2] += a.w * b.z; acc[3][3] += a.w * b.w;
  }
  #pragma unroll
  for (int i = 0; i < 4; ++i) {
    int row = (ty << 2) + i;
    float4 w = make_float4(acc[i][0], acc[i][1], acc[i][2], acc[i][3]);
    *(float4*)&out[base + row * 64 + (tx << 2)] = w;
    *(float4*)&out[8388608ull + base + row * 64 + (tx << 2)] = w;
  }
}

extern "C" void kernel_launch(void* const* d_in, const int* in_sizes, int n_in,
                              void* d_out, int out_size, void* d_ws, size_t ws_size,
                              hipStream_t stream) {
  const float* vi     = (const float*)d_in[0];
  const float* ir     = (const float*)d_in[1];
  const float* w_qkv  = (const float*)d_in[2];
  const float* proj_w = (const float*)d_in[3];
  const float* proj_b = (const float*)d_in[4];
  const float* ln_g   = (const float*)d_in[5];
  const float* ln_b   = (const float*)d_in[6];
  float* out = (float*)d_out;
  char* ws = (char*)d_ws;
  // layout (bytes):
  float*          sub  = (float*)(ws);                         // 33.5 MB BCHW fp32
  unsigned short* qkvb = (unsigned short*)(ws + 33554432);     // 50.3 MB [NPOS,768] bf16
  float*          divm = (float*)(ws + 33554432);              // reuses qkvb region, 33.5 MB fp32
  unsigned short* xnb  = (unsigned short*)(ws + 83886080);     // 16.8 MB [NPOS,256] bf16
  unsigned short* yb   = (unsigned short*)(ws + 100663296);    // 16.8 MB [NPOS,256] bf16
  unsigned short* wqb  = (unsigned short*)(ws + 117440512);    // 0.4 MB  [768,256] bf16
  unsigned short* pwb  = wqb + 196608;                         // 0.13 MB [256,256] bf16

  k_cvt<<<256, 256, 0, stream>>>(w_qkv, proj_w, wqb);
  k_sub_ln<<<1024, 256, 0, stream>>>(vi, ir, ln_g, ln_b, sub, xnb);
  k_gemm_mfma<0><<<dim3(256, 6), 256, 0, stream>>>(xnb, wqb, (void*)qkvb, nullptr, nullptr, 768);
  k_attn<<<32768, 256, 0, stream>>>(qkvb, yb);
  k_gemm_mfma<1><<<dim3(256, 2), 256, 0, stream>>>(yb, pwb, (void*)divm, proj_b, sub, 0);
  k_bmm<<<2048, 256, 0, stream>>>(vi, divm, out);
}

// Round 3
// 225.355 us; speedup vs baseline: 2.1640x; 1.4381x over previous
//
#include <hip/hip_runtime.h>
#include <math.h>

#define B_ 8
#define C_ 256
#define N_ 4096          // H*W
#define NPOS 32768       // B*N
#define SCALE_ 0.1767766952966369f
#define EPS_ 1e-5f

typedef __attribute__((ext_vector_type(8))) short bf16x8;
typedef __attribute__((ext_vector_type(8))) unsigned short u16x8;
typedef __attribute__((ext_vector_type(4))) float f32x4;

__device__ __forceinline__ unsigned short f2bf(float f) {
  union { float f; unsigned u; } v; v.f = f;
  unsigned r = v.u + 0x7fff + ((v.u >> 16) & 1);   // RNE
  return (unsigned short)(r >> 16);
}
__device__ __forceinline__ float bf2f(unsigned short u) {
  union { unsigned u; float f; } v; v.u = ((unsigned)u) << 16; return v.f;
}
__device__ __forceinline__ float blo(unsigned u) {
  union { unsigned u; float f; } v; v.u = u << 16; return v.f;
}
__device__ __forceinline__ float bhi(unsigned u) {
  union { unsigned u; float f; } v; v.u = u & 0xffff0000u; return v.f;
}

#define GLD_LDS16(g, l) \
  __builtin_amdgcn_global_load_lds((const __attribute__((address_space(1))) unsigned int*)(g), \
                                   (__attribute__((address_space(3))) unsigned int*)(l), 16, 0, 0)

// ---------------- kernel 0: convert weights to bf16 ----------------
__global__ __launch_bounds__(256) void k_cvt(
    const float* __restrict__ wq, const float* __restrict__ pw,
    unsigned short* __restrict__ dst)
{
  int i4 = blockIdx.x * 256 + threadIdx.x;          // 65536 float4s total
  float4 v = (i4 < 49152) ? ((const float4*)wq)[i4] : ((const float4*)pw)[i4 - 49152];
  ushort4 o;
  o.x = f2bf(v.x); o.y = f2bf(v.y); o.z = f2bf(v.z); o.w = f2bf(v.w);
  ((ushort4*)dst)[i4] = o;
}

// ---------------- kernel 1: sub + layernorm, bf16 xn ----------------
__global__ __launch_bounds__(256) void k_sub_ln(
    const float* __restrict__ vi, const float* __restrict__ ir,
    const float* __restrict__ ln_g, const float* __restrict__ ln_b,
    float* __restrict__ sub, unsigned short* __restrict__ xn)
{
  __shared__ float tile[C_ * 33];
  __shared__ float redS[8][32], redS2[8][32];
  __shared__ float meanS[32], rstdS[32];
  int blk = blockIdx.x;
  int b = blk >> 7;
  int y = (blk >> 1) & 63;
  int half = blk & 1;
  int t = threadIdx.x;
  size_t base = (size_t)b * C_ * N_ + (size_t)y * 64 + half * 32;
  #pragma unroll 4
  for (int it = 0; it < 32; ++it) {
    int c = it * 8 + (t >> 5);
    int x = t & 31;
    size_t g = base + (size_t)c * N_ + x;
    float s = vi[g] - ir[g];
    sub[g] = s;
    tile[c * 33 + x] = s;
  }
  __syncthreads();
  {
    int p = t & 31, grp = t >> 5;
    float s = 0.f, s2 = 0.f;
    #pragma unroll
    for (int cc = 0; cc < 32; ++cc) {
      float v = tile[(grp * 32 + cc) * 33 + p];
      s += v; s2 += v * v;
    }
    redS[grp][p] = s; redS2[grp][p] = s2;
  }
  __syncthreads();
  if (t < 32) {
    float s = 0.f, s2 = 0.f;
    #pragma unroll
    for (int g2 = 0; g2 < 8; ++g2) { s += redS[g2][t]; s2 += redS2[g2][t]; }
    float mu = s * (1.f / 256.f);
    float var = s2 * (1.f / 256.f) - mu * mu;
    meanS[t] = mu;
    rstdS[t] = rsqrtf(var + EPS_);
  }
  __syncthreads();
  int c = t;
  float gg = ln_g[c], bb = ln_b[c];
  size_t xbase = ((size_t)b * N_ + (size_t)y * 64 + half * 32) * C_;
  for (int p = 0; p < 32; ++p) {
    float v = (tile[c * 33 + p] - meanS[p]) * rstdS[p] * gg + bb;
    xn[xbase + (size_t)p * C_ + c] = f2bf(v);
  }
}

// ---------------- MFMA GEMM: C[M,N] = A[M,256] * B[N,256]^T ----------------
template<int EPI>
__global__ __launch_bounds__(256) void k_gemm_mfma(
    const unsigned short* __restrict__ A,
    const unsigned short* __restrict__ Bw,
    void* __restrict__ Cout,
    const float* __restrict__ bias,
    const float* __restrict__ sub,
    int ldc)
{
  __shared__ __align__(16) unsigned short As[128 * 32];
  __shared__ __align__(16) unsigned short Bs[128 * 32];
  int tid = threadIdx.x;
  int wv = tid >> 6;
  int lane = tid & 63;
  int m0 = blockIdx.x * 128;
  int n0 = blockIdx.y * 128;
  int mw = (wv >> 1) * 64, nw = (wv & 1) * 64;
  int r = lane & 15, q = lane >> 4;

  int seg0 = wv * 2;
  int srow0 = seg0 * 16 + (lane >> 2);
  int scol = (lane & 3) * 8;
  const unsigned short* ga0 = A  + (size_t)(m0 + srow0) * 256 + scol;
  const unsigned short* ga1 = ga0 + 16 * 256;
  const unsigned short* gb0 = Bw + (size_t)(n0 + srow0) * 256 + scol;
  const unsigned short* gb1 = gb0 + 16 * 256;
  unsigned short* la0 = &As[seg0 * 512];
  unsigned short* la1 = la0 + 512;
  unsigned short* lb0 = &Bs[seg0 * 512];
  unsigned short* lb1 = lb0 + 512;

  f32x4 acc[4][4];
  #pragma unroll
  for (int i = 0; i < 4; ++i)
    #pragma unroll
    for (int j = 0; j < 4; ++j)
      acc[i][j] = (f32x4){0.f, 0.f, 0.f, 0.f};

  for (int k0 = 0; k0 < 256; k0 += 32) {
    GLD_LDS16(ga0 + k0, la0);
    GLD_LDS16(ga1 + k0, la1);
    GLD_LDS16(gb0 + k0, lb0);
    GLD_LDS16(gb1 + k0, lb1);
    __syncthreads();
    bf16x8 af[4], bfr[4];
    #pragma unroll
    for (int mt = 0; mt < 4; ++mt)
      af[mt] = *(const bf16x8*)&As[(mw + mt * 16 + r) * 32 + q * 8];
    #pragma unroll
    for (int nt = 0; nt < 4; ++nt)
      bfr[nt] = *(const bf16x8*)&Bs[(nw + nt * 16 + r) * 32 + q * 8];
    #pragma unroll
    for (int mt = 0; mt < 4; ++mt)
      #pragma unroll
      for (int nt = 0; nt < 4; ++nt)
        acc[mt][nt] = __builtin_amdgcn_mfma_f32_16x16x32_bf16(af[mt], bfr[nt], acc[mt][nt], 0, 0, 0);
    __syncthreads();
  }

  if (EPI == 0) {
    unsigned short* C = (unsigned short*)Cout;
    #pragma unroll
    for (int mt = 0; mt < 4; ++mt)
      #pragma unroll
      for (int nt = 0; nt < 4; ++nt) {
        int n = n0 + nw + nt * 16 + r;
        #pragma unroll
        for (int rr = 0; rr < 4; ++rr) {
          int m = m0 + mw + mt * 16 + q * 4 + rr;
          C[(size_t)m * ldc + n] = f2bf(acc[mt][nt][rr]);
        }
      }
  } else {
    float* divm = (float*)Cout;
    #pragma unroll
    for (int mt = 0; mt < 4; ++mt) {
      int p0 = m0 + mw + mt * 16 + q * 4;
      int b = p0 >> 12, nn = p0 & 4095;
      #pragma unroll
      for (int nt = 0; nt < 4; ++nt) {
        int c = n0 + nw + nt * 16 + r;
        size_t idx = ((size_t)(b * 256 + c)) * 4096 + nn;
        float4 s4 = *(const float4*)&sub[idx];
        float bb = bias[c];
        float4 o;
        o.x = s4.x + bb + acc[mt][nt][0];
        o.y = s4.y + bb + acc[mt][nt][1];
        o.z = s4.z + bb + acc[mt][nt][2];
        o.w = s4.w + bb + acc[mt][nt][3];
        *(float4*)&divm[idx] = o;
      }
    }
  }
}

// ---------------- kernel 3: dilated local attention ----------------
// 4 lanes per (position, dil, head); each lane owns 8 channels (16B loads).
// Reduction over 4 lanes = 2 DPP quad-perm shuffles. __expf = v_exp_f32.
__global__ __launch_bounds__(256) void k_attn(
    const unsigned short* __restrict__ qkv,   // [NPOS, 768] bf16
    unsigned short* __restrict__ y)           // [NPOS, 256] bf16
{
  int t = threadIdx.x;
  int sub = t >> 2;                 // 64 subgroups per block
  int lane4 = t & 3;
  int item = blockIdx.x * 64 + sub; // (p, i, h)
  int ih = item & 7;
  int p = item >> 3;
  int i = ih >> 1, h = ih & 1;
  int dil = i + 1;                  // DIL = (1,2,3,4)
  int b = p >> 12;
  int n = p & 4095;
  int py = n >> 6, px = n & 63;
  int off = i * 64 + h * 32 + lane4 * 8;
  const unsigned short* base = qkv + off;

  uint4 qw = *(const uint4*)(base + (size_t)p * 768);
  float q0 = blo(qw.x), q1 = bhi(qw.x), q2 = blo(qw.y), q3 = bhi(qw.y),
        q4 = blo(qw.z), q5 = bhi(qw.z), q6 = blo(qw.w), q7 = bhi(qw.w);

  // tap positions (subgroup-uniform); pj < 0 marks out-of-bounds (zero pad)
  int pj[9];
  #pragma unroll
  for (int j = 0; j < 9; ++j) {
    int ny = py + (j / 3 - 1) * dil;
    int nx = px + (j % 3 - 1) * dil;
    bool ok = ((unsigned)ny < 64u) && ((unsigned)nx < 64u);
    pj[j] = ok ? ((b << 12) + (ny << 6) + nx) : -1;
  }

  float sc[9];
  #pragma unroll
  for (int j = 0; j < 9; ++j) {
    float s = 0.f;
    if (pj[j] >= 0) {
      uint4 kw = *(const uint4*)(base + 256 + (size_t)pj[j] * 768);
      s  = q0 * blo(kw.x) + q1 * bhi(kw.x);
      s += q2 * blo(kw.y) + q3 * bhi(kw.y);
      s += q4 * blo(kw.z) + q5 * bhi(kw.z);
      s += q6 * blo(kw.w) + q7 * bhi(kw.w);
    }
    s += __shfl_xor(s, 1, 4);
    s += __shfl_xor(s, 2, 4);
    sc[j] = s * SCALE_;             // OOB taps give score exactly 0 (zero pad)
  }

  float mx = sc[0];
  #pragma unroll
  for (int j = 1; j < 9; ++j) mx = fmaxf(mx, sc[j]);
  float e[9], ssum = 0.f;
  #pragma unroll
  for (int j = 0; j < 9; ++j) { e[j] = __expf(sc[j] - mx); ssum += e[j]; }
  float inv = 1.f / ssum;

  float o0 = 0.f, o1 = 0.f, o2 = 0.f, o3 = 0.f, o4 = 0.f, o5 = 0.f, o6 = 0.f, o7 = 0.f;
  #pragma unroll
  for (int j = 0; j < 9; ++j) {
    if (pj[j] >= 0) {
      float w = e[j] * inv;
      uint4 vw = *(const uint4*)(base + 512 + (size_t)pj[j] * 768);
      o0 += w * blo(vw.x); o1 += w * bhi(vw.x);
      o2 += w * blo(vw.y); o3 += w * bhi(vw.y);
      o4 += w * blo(vw.z); o5 += w * bhi(vw.z);
      o6 += w * blo(vw.w); o7 += w * bhi(vw.w);
    }
  }

  u16x8 ov;
  ov[0] = f2bf(o0); ov[1] = f2bf(o1); ov[2] = f2bf(o2); ov[3] = f2bf(o3);
  ov[4] = f2bf(o4); ov[5] = f2bf(o5); ov[6] = f2bf(o6); ov[7] = f2bf(o7);
  *(u16x8*)(y + (size_t)p * 256 + off) = ov;
}

// ---------------- kernel 5: per-(b,c) 64x64x64 matmul, dup output ----------
__global__ __launch_bounds__(256) void k_bmm(
    const float* __restrict__ vi, const float* __restrict__ divm,
    float* __restrict__ out)
{
  __shared__ float At[64 * 68];
  __shared__ float Bsm[64 * 64];
  int bc = blockIdx.x;
  size_t base = (size_t)bc * 4096;
  int t = threadIdx.x;
  #pragma unroll
  for (int it = 0; it < 4; ++it) {
    int flat = it * 1024 + t * 4;
    int row = flat >> 6, col = flat & 63;
    float4 a = *(const float4*)&vi[base + flat];
    float4 bv = *(const float4*)&divm[base + flat];
    At[(col + 0) * 68 + row] = a.x;
    At[(col + 1) * 68 + row] = a.y;
    At[(col + 2) * 68 + row] = a.z;
    At[(col + 3) * 68 + row] = a.w;
    *(float4*)&Bsm[flat] = bv;
  }
  __syncthreads();
  int tx = t & 15, ty = t >> 4;
  float acc[4][4] = {};
  for (int k = 0; k < 64; ++k) {
    float4 a = *(const float4*)&At[k * 68 + (ty << 2)];
    float4 b = *(const float4*)&Bsm[k * 64 + (tx << 2)];
    acc[0][0] += a.x * b.x; acc[0][1] += a.x * b.y; acc[0][2] += a.x * b.z; acc[0][3] += a.x * b.w;
    acc[1][0] += a.y * b.x; acc[1][1] += a.y * b.y; acc[1][2] += a.y * b.z; acc[1][3] += a.y * b.w;
    acc[2][0] += a.z * b.x; acc[2][1] += a.z * b.y; acc[2][2] += a.z * b.z; acc[2][3] += a.z * b.w;
    acc[3][0] += a.w * b.x; acc[3][1] += a.w * b.y; acc[3][2] += a.w * b.z; acc[3][3] += a.w * b.w;
  }
  #pragma unroll
  for (int i = 0; i < 4; ++i) {
    int row = (ty << 2) + i;
    float4 w = make_float4(acc[i][0], acc[i][1], acc[i][2], acc[i][3]);
    *(float4*)&out[base + row * 64 + (tx << 2)] = w;
    *(float4*)&out[8388608ull + base + row * 64 + (tx << 2)] = w;
  }
}

extern "C" void kernel_launch(void* const* d_in, const int* in_sizes, int n_in,
                              void* d_out, int out_size, void* d_ws, size_t ws_size,
                              hipStream_t stream) {
  const float* vi     = (const float*)d_in[0];
  const float* ir     = (const float*)d_in[1];
  const float* w_qkv  = (const float*)d_in[2];
  const float* proj_w = (const float*)d_in[3];
  const float* proj_b = (const float*)d_in[4];
  const float* ln_g   = (const float*)d_in[5];
  const float* ln_b   = (const float*)d_in[6];
  float* out = (float*)d_out;
  char* ws = (char*)d_ws;
  float*          sub  = (float*)(ws);                         // 33.5 MB BCHW fp32
  unsigned short* qkvb = (unsigned short*)(ws + 33554432);     // 50.3 MB [NPOS,768] bf16
  float*          divm = (float*)(ws + 33554432);              // reuses qkvb region
  unsigned short* xnb  = (unsigned short*)(ws + 83886080);     // 16.8 MB [NPOS,256] bf16
  unsigned short* yb   = (unsigned short*)(ws + 100663296);    // 16.8 MB [NPOS,256] bf16
  unsigned short* wqb  = (unsigned short*)(ws + 117440512);    // [768,256] bf16
  unsigned short* pwb  = wqb + 196608;                         // [256,256] bf16

  k_cvt<<<256, 256, 0, stream>>>(w_qkv, proj_w, wqb);
  k_sub_ln<<<1024, 256, 0, stream>>>(vi, ir, ln_g, ln_b, sub, xnb);
  k_gemm_mfma<0><<<dim3(256, 6), 256, 0, stream>>>(xnb, wqb, (void*)qkvb, nullptr, nullptr, 768);
  k_attn<<<4096, 256, 0, stream>>>(qkvb, yb);
  k_gemm_mfma<1><<<dim3(256, 2), 256, 0, stream>>>(yb, pwb, (void*)divm, proj_b, sub, 0);
  k_bmm<<<2048, 256, 0, stream>>>(vi, divm, out);
}

// Round 4
// 215.357 us; speedup vs baseline: 2.2645x; 1.0464x over previous
//
#include <hip/hip_runtime.h>
#include <math.h>

#define B_ 8
#define C_ 256
#define N_ 4096          // H*W
#define NPOS 32768       // B*N
#define SCALE_ 0.1767766952966369f
#define EPS_ 1e-5f

typedef __attribute__((ext_vector_type(8))) short bf16x8;
typedef __attribute__((ext_vector_type(8))) unsigned short u16x8;
typedef __attribute__((ext_vector_type(4))) unsigned short u16x4;
typedef __attribute__((ext_vector_type(4))) float f32x4;

__device__ __forceinline__ unsigned short f2bf(float f) {
  union { float f; unsigned u; } v; v.f = f;
  unsigned r = v.u + 0x7fff + ((v.u >> 16) & 1);   // RNE
  return (unsigned short)(r >> 16);
}
__device__ __forceinline__ float bf2f(unsigned short u) {
  union { unsigned u; float f; } v; v.u = ((unsigned)u) << 16; return v.f;
}
__device__ __forceinline__ float blo(unsigned u) {
  union { unsigned u; float f; } v; v.u = u << 16; return v.f;
}
__device__ __forceinline__ float bhi(unsigned u) {
  union { unsigned u; float f; } v; v.u = u & 0xffff0000u; return v.f;
}

#define GLD_LDS16(g, l) \
  __builtin_amdgcn_global_load_lds((const __attribute__((address_space(1))) unsigned int*)(g), \
                                   (__attribute__((address_space(3))) unsigned int*)(l), 16, 0, 0)

// ---------------- kernel 0: convert weights to bf16 ----------------
__global__ __launch_bounds__(256) void k_cvt(
    const float* __restrict__ wq, const float* __restrict__ pw,
    unsigned short* __restrict__ dst)
{
  int i4 = blockIdx.x * 256 + threadIdx.x;          // 65536 float4s total
  float4 v = (i4 < 49152) ? ((const float4*)wq)[i4] : ((const float4*)pw)[i4 - 49152];
  ushort4 o;
  o.x = f2bf(v.x); o.y = f2bf(v.y); o.z = f2bf(v.z); o.w = f2bf(v.w);
  ((ushort4*)dst)[i4] = o;
}

// ---------------- kernel 1: sub + layernorm -> bf16 sub (BCHW) + bf16 xn ---
__global__ __launch_bounds__(256) void k_sub_ln(
    const float* __restrict__ vi, const float* __restrict__ ir,
    const float* __restrict__ ln_g, const float* __restrict__ ln_b,
    unsigned short* __restrict__ subB, unsigned short* __restrict__ xn)
{
  __shared__ float tile[C_ * 33];          // [c][x] stride 33
  __shared__ float redS[8][32], redS2[8][32];
  __shared__ float meanS[32], rstdS[32];
  int blk = blockIdx.x;                    // b*128 + y*2 + half
  int b = blk >> 7;
  int y = (blk >> 1) & 63;
  int half = blk & 1;
  int t = threadIdx.x;
  size_t base = (size_t)b * C_ * N_ + (size_t)y * 64 + half * 32;
  #pragma unroll
  for (int it = 0; it < 8; ++it) {
    int c = it * 32 + (t >> 3);
    int xq = (t & 7) * 4;
    size_t g = base + (size_t)c * N_ + xq;
    float4 v4 = *(const float4*)&vi[g];
    float4 i4 = *(const float4*)&ir[g];
    float4 s4;
    s4.x = v4.x - i4.x; s4.y = v4.y - i4.y; s4.z = v4.z - i4.z; s4.w = v4.w - i4.w;
    ushort4 sb;
    sb.x = f2bf(s4.x); sb.y = f2bf(s4.y); sb.z = f2bf(s4.z); sb.w = f2bf(s4.w);
    *(ushort4*)&subB[g] = sb;
    tile[c * 33 + xq + 0] = s4.x;
    tile[c * 33 + xq + 1] = s4.y;
    tile[c * 33 + xq + 2] = s4.z;
    tile[c * 33 + xq + 3] = s4.w;
  }
  __syncthreads();
  {
    int p = t & 31, grp = t >> 5;
    float s = 0.f, s2 = 0.f;
    #pragma unroll
    for (int cc = 0; cc < 32; ++cc) {
      float v = tile[(grp * 32 + cc) * 33 + p];
      s += v; s2 += v * v;
    }
    redS[grp][p] = s; redS2[grp][p] = s2;
  }
  __syncthreads();
  if (t < 32) {
    float s = 0.f, s2 = 0.f;
    #pragma unroll
    for (int g2 = 0; g2 < 8; ++g2) { s += redS[g2][t]; s2 += redS2[g2][t]; }
    float mu = s * (1.f / 256.f);
    float var = s2 * (1.f / 256.f) - mu * mu;
    meanS[t] = mu;
    rstdS[t] = rsqrtf(var + EPS_);
  }
  __syncthreads();
  int c = t;
  float gg = ln_g[c], bb = ln_b[c];
  size_t xbase = ((size_t)b * N_ + (size_t)y * 64 + half * 32) * C_;
  for (int p = 0; p < 32; ++p) {
    float v = (tile[c * 33 + p] - meanS[p]) * rstdS[p] * gg + bb;
    xn[xbase + (size_t)p * C_ + c] = f2bf(v);
  }
}

// ---------------- MFMA GEMM: C[M,N] = A[M,256] * B[N,256]^T ----------------
// 128x128 tile, 4 waves. EPI 0: bf16 C row-major (ldc) via LDS-bounce
// coalesced stores. EPI 1: proj epilogue -> bf16 divm in BCHW, bias+residual
// applied in the coalesced copy stage (channel-major bounce).
template<int EPI>
__global__ __launch_bounds__(256) void k_gemm_mfma(
    const unsigned short* __restrict__ A,
    const unsigned short* __restrict__ Bw,
    unsigned short* __restrict__ Cout,
    const float* __restrict__ bias,
    const unsigned short* __restrict__ subB,
    int ldc)
{
  __shared__ __align__(16) unsigned short As[128 * 32];
  __shared__ __align__(16) unsigned short Bs[128 * 32];
  __shared__ __align__(16) unsigned short Cs[64 * 136];   // bounce, pad 136
  int tid = threadIdx.x;
  int wv = tid >> 6;
  int lane = tid & 63;
  int m0 = blockIdx.x * 128;
  int n0 = blockIdx.y * 128;
  int mw = (wv >> 1) * 64, nw = (wv & 1) * 64;
  int r = lane & 15, q = lane >> 4;

  int seg0 = wv * 2;
  int srow0 = seg0 * 16 + (lane >> 2);
  int scol = (lane & 3) * 8;
  const unsigned short* ga0 = A  + (size_t)(m0 + srow0) * 256 + scol;
  const unsigned short* ga1 = ga0 + 16 * 256;
  const unsigned short* gb0 = Bw + (size_t)(n0 + srow0) * 256 + scol;
  const unsigned short* gb1 = gb0 + 16 * 256;
  unsigned short* la0 = &As[seg0 * 512];
  unsigned short* la1 = la0 + 512;
  unsigned short* lb0 = &Bs[seg0 * 512];
  unsigned short* lb1 = lb0 + 512;

  f32x4 acc[4][4];
  #pragma unroll
  for (int i = 0; i < 4; ++i)
    #pragma unroll
    for (int j = 0; j < 4; ++j)
      acc[i][j] = (f32x4){0.f, 0.f, 0.f, 0.f};

  for (int k0 = 0; k0 < 256; k0 += 32) {
    GLD_LDS16(ga0 + k0, la0);
    GLD_LDS16(ga1 + k0, la1);
    GLD_LDS16(gb0 + k0, lb0);
    GLD_LDS16(gb1 + k0, lb1);
    __syncthreads();
    bf16x8 af[4], bfr[4];
    #pragma unroll
    for (int mt = 0; mt < 4; ++mt)
      af[mt] = *(const bf16x8*)&As[(mw + mt * 16 + r) * 32 + q * 8];
    #pragma unroll
    for (int nt = 0; nt < 4; ++nt)
      bfr[nt] = *(const bf16x8*)&Bs[(nw + nt * 16 + r) * 32 + q * 8];
    #pragma unroll
    for (int mt = 0; mt < 4; ++mt)
      #pragma unroll
      for (int nt = 0; nt < 4; ++nt)
        acc[mt][nt] = __builtin_amdgcn_mfma_f32_16x16x32_bf16(af[mt], bfr[nt], acc[mt][nt], 0, 0, 0);
    __syncthreads();
  }

  int b = m0 >> 12;            // EPI1: batch (m0 is 128-aligned inside 4096)
  int nn0 = m0 & 4095;
  #pragma unroll
  for (int pass = 0; pass < 2; ++pass) {
    __syncthreads();           // Cs reuse across passes
    if (EPI == 0) {
      // rows pass*64..pass*64+63 (position-major): waves with mw==pass*64
      if ((wv >> 1) == pass) {
        #pragma unroll
        for (int mt = 0; mt < 4; ++mt) {
          int lr = mt * 16 + q * 4;
          #pragma unroll
          for (int nt = 0; nt < 4; ++nt) {
            int col = nw + nt * 16 + r;
            #pragma unroll
            for (int rr = 0; rr < 4; ++rr)
              Cs[(lr + rr) * 136 + col] = f2bf(acc[mt][nt][rr]);
          }
        }
      }
    } else {
      // channel-major: rows = channels pass*64..+63: waves with nw==pass*64
      if ((wv & 1) == pass) {
        #pragma unroll
        for (int nt = 0; nt < 4; ++nt) {
          int lr = nt * 16 + r;           // channel-local row
          #pragma unroll
          for (int mt = 0; mt < 4; ++mt) {
            int pc = mw + mt * 16 + q * 4; // position-local col
            #pragma unroll
            for (int rr = 0; rr < 4; ++rr)
              Cs[lr * 136 + pc + rr] = f2bf(acc[mt][nt][rr]);
          }
        }
      }
    }
    __syncthreads();
    if (EPI == 0) {
      #pragma unroll
      for (int cc = 0; cc < 4; ++cc) {
        int ch = cc * 256 + tid;          // 1024 16B-chunks: 64 rows x 16
        int row = ch >> 4, cg = ch & 15;
        u16x8 cv = *(const u16x8*)&Cs[row * 136 + cg * 8];
        int m = m0 + pass * 64 + row;
        *(u16x8*)&Cout[(size_t)m * ldc + n0 + cg * 8] = cv;
      }
    } else {
      #pragma unroll
      for (int cc = 0; cc < 4; ++cc) {
        int ch = cc * 256 + tid;
        int row = ch >> 4, cg = ch & 15;  // row = channel-local, cg*8 = pos
        u16x8 cv = *(const u16x8*)&Cs[row * 136 + cg * 8];
        int c = n0 + pass * 64 + row;
        size_t idx = ((size_t)(b * 256 + c)) * 4096 + nn0 + cg * 8;
        u16x8 sv = *(const u16x8*)&subB[idx];
        float bb = bias[c];
        u16x8 ov;
        #pragma unroll
        for (int e = 0; e < 8; ++e)
          ov[e] = f2bf(bf2f((unsigned short)cv[e]) + bb + bf2f((unsigned short)sv[e]));
        *(u16x8*)&Cout[idx] = ov;
      }
    }
  }
}

// ---------------- kernel 3: dilated local attention ----------------
// 4 lanes per (position, dil, head); each lane owns 8 channels (16B loads).
__global__ __launch_bounds__(256) void k_attn(
    const unsigned short* __restrict__ qkv,   // [NPOS, 768] bf16
    unsigned short* __restrict__ y)           // [NPOS, 256] bf16
{
  int t = threadIdx.x;
  int sub = t >> 2;
  int lane4 = t & 3;
  int item = blockIdx.x * 64 + sub;
  int ih = item & 7;
  int p = item >> 3;
  int i = ih >> 1, h = ih & 1;
  int dil = i + 1;
  int b = p >> 12;
  int n = p & 4095;
  int py = n >> 6, px = n & 63;
  int off = i * 64 + h * 32 + lane4 * 8;
  const unsigned short* base = qkv + off;

  uint4 qw = *(const uint4*)(base + (size_t)p * 768);
  float q0 = blo(qw.x), q1 = bhi(qw.x), q2 = blo(qw.y), q3 = bhi(qw.y),
        q4 = blo(qw.z), q5 = bhi(qw.z), q6 = blo(qw.w), q7 = bhi(qw.w);

  int pj[9];
  #pragma unroll
  for (int j = 0; j < 9; ++j) {
    int ny = py + (j / 3 - 1) * dil;
    int nx = px + (j % 3 - 1) * dil;
    bool ok = ((unsigned)ny < 64u) && ((unsigned)nx < 64u);
    pj[j] = ok ? ((b << 12) + (ny << 6) + nx) : -1;
  }

  float sc[9];
  #pragma unroll
  for (int j = 0; j < 9; ++j) {
    float s = 0.f;
    if (pj[j] >= 0) {
      uint4 kw = *(const uint4*)(base + 256 + (size_t)pj[j] * 768);
      s  = q0 * blo(kw.x) + q1 * bhi(kw.x);
      s += q2 * blo(kw.y) + q3 * bhi(kw.y);
      s += q4 * blo(kw.z) + q5 * bhi(kw.z);
      s += q6 * blo(kw.w) + q7 * bhi(kw.w);
    }
    s += __shfl_xor(s, 1, 4);
    s += __shfl_xor(s, 2, 4);
    sc[j] = s * SCALE_;             // zero-pad taps -> score exactly 0
  }

  float mx = sc[0];
  #pragma unroll
  for (int j = 1; j < 9; ++j) mx = fmaxf(mx, sc[j]);
  float e[9], ssum = 0.f;
  #pragma unroll
  for (int j = 0; j < 9; ++j) { e[j] = __expf(sc[j] - mx); ssum += e[j]; }
  float inv = 1.f / ssum;

  float o0 = 0.f, o1 = 0.f, o2 = 0.f, o3 = 0.f, o4 = 0.f, o5 = 0.f, o6 = 0.f, o7 = 0.f;
  #pragma unroll
  for (int j = 0; j < 9; ++j) {
    if (pj[j] >= 0) {
      float w = e[j] * inv;
      uint4 vw = *(const uint4*)(base + 512 + (size_t)pj[j] * 768);
      o0 += w * blo(vw.x); o1 += w * bhi(vw.x);
      o2 += w * blo(vw.y); o3 += w * bhi(vw.y);
      o4 += w * blo(vw.z); o5 += w * bhi(vw.z);
      o6 += w * blo(vw.w); o7 += w * bhi(vw.w);
    }
  }

  u16x8 ov;
  ov[0] = f2bf(o0); ov[1] = f2bf(o1); ov[2] = f2bf(o2); ov[3] = f2bf(o3);
  ov[4] = f2bf(o4); ov[5] = f2bf(o5); ov[6] = f2bf(o6); ov[7] = f2bf(o7);
  *(u16x8*)(y + (size_t)p * 256 + off) = ov;
}

// ---------------- kernel 5: per-(b,c) 64x64x64 matmul, dup output ----------
__global__ __launch_bounds__(256) void k_bmm(
    const float* __restrict__ vi, const unsigned short* __restrict__ divmB,
    float* __restrict__ out)
{
  __shared__ float At[64 * 68];   // transposed vi: At[k][i]
  __shared__ float Bsm[64 * 64];  // div row-major [k][j], fp32 from bf16
  int bc = blockIdx.x;
  size_t base = (size_t)bc * 4096;
  int t = threadIdx.x;
  #pragma unroll
  for (int it = 0; it < 4; ++it) {
    int flat = it * 1024 + t * 4;
    int row = flat >> 6, col = flat & 63;
    float4 a = *(const float4*)&vi[base + flat];
    At[(col + 0) * 68 + row] = a.x;
    At[(col + 1) * 68 + row] = a.y;
    At[(col + 2) * 68 + row] = a.z;
    At[(col + 3) * 68 + row] = a.w;
  }
  #pragma unroll
  for (int it = 0; it < 2; ++it) {
    int flat = it * 2048 + t * 8;
    u16x8 dv = *(const u16x8*)&divmB[base + flat];
    float4 lo, hi;
    lo.x = bf2f((unsigned short)dv[0]); lo.y = bf2f((unsigned short)dv[1]);
    lo.z = bf2f((unsigned short)dv[2]); lo.w = bf2f((unsigned short)dv[3]);
    hi.x = bf2f((unsigned short)dv[4]); hi.y = bf2f((unsigned short)dv[5]);
    hi.z = bf2f((unsigned short)dv[6]); hi.w = bf2f((unsigned short)dv[7]);
    *(float4*)&Bsm[flat] = lo;
    *(float4*)&Bsm[flat + 4] = hi;
  }
  __syncthreads();
  int tx = t & 15, ty = t >> 4;
  float acc[4][4] = {};
  for (int k = 0; k < 64; ++k) {
    float4 a = *(const float4*)&At[k * 68 + (ty << 2)];
    float4 b = *(const float4*)&Bsm[k * 64 + (tx << 2)];
    acc[0][0] += a.x * b.x; acc[0][1] += a.x * b.y; acc[0][2] += a.x * b.z; acc[0][3] += a.x * b.w;
    acc[1][0] += a.y * b.x; acc[1][1] += a.y * b.y; acc[1][2] += a.y * b.z; acc[1][3] += a.y * b.w;
    acc[2][0] += a.z * b.x; acc[2][1] += a.z * b.y; acc[2][2] += a.z * b.z; acc[2][3] += a.z * b.w;
    acc[3][0] += a.w * b.x; acc[3][1] += a.w * b.y; acc[3][2] += a.w * b.z; acc[3][3] += a.w * b.w;
  }
  #pragma unroll
  for (int i = 0; i < 4; ++i) {
    int row = (ty << 2) + i;
    float4 w = make_float4(acc[i][0], acc[i][1], acc[i][2], acc[i][3]);
    *(float4*)&out[base + row * 64 + (tx << 2)] = w;
    *(float4*)&out[8388608ull + base + row * 64 + (tx << 2)] = w;
  }
}

extern "C" void kernel_launch(void* const* d_in, const int* in_sizes, int n_in,
                              void* d_out, int out_size, void* d_ws, size_t ws_size,
                              hipStream_t stream) {
  const float* vi     = (const float*)d_in[0];
  const float* ir     = (const float*)d_in[1];
  const float* w_qkv  = (const float*)d_in[2];
  const float* proj_w = (const float*)d_in[3];
  const float* proj_b = (const float*)d_in[4];
  const float* ln_g   = (const float*)d_in[5];
  const float* ln_b   = (const float*)d_in[6];
  float* out = (float*)d_out;
  char* ws = (char*)d_ws;
  unsigned short* subB = (unsigned short*)(ws);                // 16.8 MB BCHW bf16
  unsigned short* qkvb = (unsigned short*)(ws + 16777216);     // 50.3 MB [NPOS,768] bf16
  unsigned short* divmB= (unsigned short*)(ws + 16777216);     // reuses qkvb region, 16.8 MB bf16 BCHW
  unsigned short* xnb  = (unsigned short*)(ws + 67108864);     // 16.8 MB [NPOS,256] bf16
  unsigned short* yb   = (unsigned short*)(ws + 83886080);     // 16.8 MB [NPOS,256] bf16
  unsigned short* wqb  = (unsigned short*)(ws + 100663296);    // [768,256] bf16
  unsigned short* pwb  = wqb + 196608;                         // [256,256] bf16

  k_cvt<<<256, 256, 0, stream>>>(w_qkv, proj_w, wqb);
  k_sub_ln<<<1024, 256, 0, stream>>>(vi, ir, ln_g, ln_b, subB, xnb);
  k_gemm_mfma<0><<<dim3(256, 6), 256, 0, stream>>>(xnb, wqb, qkvb, nullptr, nullptr, 768);
  k_attn<<<4096, 256, 0, stream>>>(qkvb, yb);
  k_gemm_mfma<1><<<dim3(256, 2), 256, 0, stream>>>(yb, pwb, divmB, proj_b, subB, 0);
  k_bmm<<<2048, 256, 0, stream>>>(vi, divmB, out);
}

// Round 5
// 211.354 us; speedup vs baseline: 2.3074x; 1.0189x over previous
//
#include <hip/hip_runtime.h>
#include <math.h>

#define B_ 8
#define C_ 256
#define N_ 4096          // H*W
#define NPOS 32768       // B*N
#define SCALE_ 0.1767766952966369f
#define EPS_ 1e-5f

typedef __attribute__((ext_vector_type(8))) short bf16x8;
typedef __attribute__((ext_vector_type(8))) unsigned short u16x8;
typedef __attribute__((ext_vector_type(4))) float f32x4;

__device__ __forceinline__ unsigned short f2bf(float f) {
  union { float f; unsigned u; } v; v.f = f;
  unsigned r = v.u + 0x7fff + ((v.u >> 16) & 1);   // RNE
  return (unsigned short)(r >> 16);
}
__device__ __forceinline__ float bf2f(unsigned short u) {
  union { unsigned u; float f; } v; v.u = ((unsigned)u) << 16; return v.f;
}
__device__ __forceinline__ float blo(unsigned u) {
  union { unsigned u; float f; } v; v.u = u << 16; return v.f;
}
__device__ __forceinline__ float bhi(unsigned u) {
  union { unsigned u; float f; } v; v.u = u & 0xffff0000u; return v.f;
}

#define GLD_LDS16(g, l) \
  __builtin_amdgcn_global_load_lds((const __attribute__((address_space(1))) unsigned int*)(g), \
                                   (__attribute__((address_space(3))) unsigned int*)(l), 16, 0, 0)

// ---- kernel 1: [blocks 0..255] weight cvt  [blocks 256..1279] sub+LN ----
// sub_ln: writes subB bf16 (BCHW), viB bf16 (BCHW), xn bf16 [NPOS,256]
__global__ __launch_bounds__(256) void k_pre(
    const float* __restrict__ vi, const float* __restrict__ ir,
    const float* __restrict__ wq, const float* __restrict__ pw,
    const float* __restrict__ ln_g, const float* __restrict__ ln_b,
    unsigned short* __restrict__ wdst,
    unsigned short* __restrict__ subB, unsigned short* __restrict__ viB,
    unsigned short* __restrict__ xn)
{
  __shared__ float tile[C_ * 33];
  __shared__ float redS[8][32], redS2[8][32];
  __shared__ float meanS[32], rstdS[32];
  int t = threadIdx.x;
  if (blockIdx.x < 256) {
    int i4 = blockIdx.x * 256 + t;   // 65536 float4s
    float4 v = (i4 < 49152) ? ((const float4*)wq)[i4] : ((const float4*)pw)[i4 - 49152];
    ushort4 o;
    o.x = f2bf(v.x); o.y = f2bf(v.y); o.z = f2bf(v.z); o.w = f2bf(v.w);
    ((ushort4*)wdst)[i4] = o;
    return;
  }
  int blk = blockIdx.x - 256;              // b*128 + y*2 + half
  int b = blk >> 7;
  int y = (blk >> 1) & 63;
  int half = blk & 1;
  size_t base = (size_t)b * C_ * N_ + (size_t)y * 64 + half * 32;
  #pragma unroll
  for (int it = 0; it < 8; ++it) {
    int c = it * 32 + (t >> 3);
    int xq = (t & 7) * 4;
    size_t g = base + (size_t)c * N_ + xq;
    float4 v4 = *(const float4*)&vi[g];
    float4 i4 = *(const float4*)&ir[g];
    float4 s4;
    s4.x = v4.x - i4.x; s4.y = v4.y - i4.y; s4.z = v4.z - i4.z; s4.w = v4.w - i4.w;
    ushort4 sb, vb;
    sb.x = f2bf(s4.x); sb.y = f2bf(s4.y); sb.z = f2bf(s4.z); sb.w = f2bf(s4.w);
    vb.x = f2bf(v4.x); vb.y = f2bf(v4.y); vb.z = f2bf(v4.z); vb.w = f2bf(v4.w);
    *(ushort4*)&subB[g] = sb;
    *(ushort4*)&viB[g] = vb;
    tile[c * 33 + xq + 0] = s4.x;
    tile[c * 33 + xq + 1] = s4.y;
    tile[c * 33 + xq + 2] = s4.z;
    tile[c * 33 + xq + 3] = s4.w;
  }
  __syncthreads();
  {
    int p = t & 31, grp = t >> 5;
    float s = 0.f, s2 = 0.f;
    #pragma unroll
    for (int cc = 0; cc < 32; ++cc) {
      float v = tile[(grp * 32 + cc) * 33 + p];
      s += v; s2 += v * v;
    }
    redS[grp][p] = s; redS2[grp][p] = s2;
  }
  __syncthreads();
  if (t < 32) {
    float s = 0.f, s2 = 0.f;
    #pragma unroll
    for (int g2 = 0; g2 < 8; ++g2) { s += redS[g2][t]; s2 += redS2[g2][t]; }
    float mu = s * (1.f / 256.f);
    float var = s2 * (1.f / 256.f) - mu * mu;
    meanS[t] = mu;
    rstdS[t] = rsqrtf(var + EPS_);
  }
  __syncthreads();
  int c = t;
  float gg = ln_g[c], bb = ln_b[c];
  size_t xbase = ((size_t)b * N_ + (size_t)y * 64 + half * 32) * C_;
  for (int p = 0; p < 32; ++p) {
    float v = (tile[c * 33 + p] - meanS[p]) * rstdS[p] * gg + bb;
    xn[xbase + (size_t)p * C_ + c] = f2bf(v);
  }
}

// ---------------- MFMA GEMM: C[M,N] = A[M,256] * B[N,256]^T ----------------
// Flat grid, XCD-aware swizzle: blocks sharing one A m-tile land on one XCD
// (flat%8 = XCD on MI355X round-robin dispatch) -> A re-reads hit L2.
// NT = number of 128-wide n-tiles (6 for qkv, 2 for proj).
template<int EPI, int NT>
__global__ __launch_bounds__(256) void k_gemm_mfma(
    const unsigned short* __restrict__ A,
    const unsigned short* __restrict__ Bw,
    unsigned short* __restrict__ Cout,
    const float* __restrict__ bias,
    const unsigned short* __restrict__ subB,
    int ldc)
{
  __shared__ __align__(16) unsigned short As[128 * 32];
  __shared__ __align__(16) unsigned short Bs[128 * 32];
  __shared__ __align__(16) unsigned short Cs[64 * 136];
  int flat = blockIdx.x;
  int xcd = flat & 7;
  int l = flat >> 3;
  int ml = l / NT;
  int nn = l - ml * NT;
  int m0 = (xcd * 32 + ml) * 128;
  int n0 = nn * 128;
  int tid = threadIdx.x;
  int wv = tid >> 6;
  int lane = tid & 63;
  int mw = (wv >> 1) * 64, nw = (wv & 1) * 64;
  int r = lane & 15, q = lane >> 4;

  int seg0 = wv * 2;
  int srow0 = seg0 * 16 + (lane >> 2);
  int scol = (lane & 3) * 8;
  const unsigned short* ga0 = A  + (size_t)(m0 + srow0) * 256 + scol;
  const unsigned short* ga1 = ga0 + 16 * 256;
  const unsigned short* gb0 = Bw + (size_t)(n0 + srow0) * 256 + scol;
  const unsigned short* gb1 = gb0 + 16 * 256;
  unsigned short* la0 = &As[seg0 * 512];
  unsigned short* la1 = la0 + 512;
  unsigned short* lb0 = &Bs[seg0 * 512];
  unsigned short* lb1 = lb0 + 512;

  f32x4 acc[4][4];
  #pragma unroll
  for (int i = 0; i < 4; ++i)
    #pragma unroll
    for (int j = 0; j < 4; ++j)
      acc[i][j] = (f32x4){0.f, 0.f, 0.f, 0.f};

  for (int k0 = 0; k0 < 256; k0 += 32) {
    GLD_LDS16(ga0 + k0, la0);
    GLD_LDS16(ga1 + k0, la1);
    GLD_LDS16(gb0 + k0, lb0);
    GLD_LDS16(gb1 + k0, lb1);
    __syncthreads();
    bf16x8 af[4], bfr[4];
    #pragma unroll
    for (int mt = 0; mt < 4; ++mt)
      af[mt] = *(const bf16x8*)&As[(mw + mt * 16 + r) * 32 + q * 8];
    #pragma unroll
    for (int nt = 0; nt < 4; ++nt)
      bfr[nt] = *(const bf16x8*)&Bs[(nw + nt * 16 + r) * 32 + q * 8];
    #pragma unroll
    for (int mt = 0; mt < 4; ++mt)
      #pragma unroll
      for (int nt = 0; nt < 4; ++nt)
        acc[mt][nt] = __builtin_amdgcn_mfma_f32_16x16x32_bf16(af[mt], bfr[nt], acc[mt][nt], 0, 0, 0);
    __syncthreads();
  }

  int b = m0 >> 12;
  int nn0 = m0 & 4095;
  #pragma unroll
  for (int pass = 0; pass < 2; ++pass) {
    __syncthreads();
    if (EPI == 0) {
      if ((wv >> 1) == pass) {
        #pragma unroll
        for (int mt = 0; mt < 4; ++mt) {
          int lr = mt * 16 + q * 4;
          #pragma unroll
          for (int nt = 0; nt < 4; ++nt) {
            int col = nw + nt * 16 + r;
            #pragma unroll
            for (int rr = 0; rr < 4; ++rr)
              Cs[(lr + rr) * 136 + col] = f2bf(acc[mt][nt][rr]);
          }
        }
      }
    } else {
      if ((wv & 1) == pass) {
        #pragma unroll
        for (int nt = 0; nt < 4; ++nt) {
          int lr = nt * 16 + r;
          #pragma unroll
          for (int mt = 0; mt < 4; ++mt) {
            int pc = mw + mt * 16 + q * 4;
            #pragma unroll
            for (int rr = 0; rr < 4; ++rr)
              Cs[lr * 136 + pc + rr] = f2bf(acc[mt][nt][rr]);
          }
        }
      }
    }
    __syncthreads();
    if (EPI == 0) {
      #pragma unroll
      for (int cc = 0; cc < 4; ++cc) {
        int ch = cc * 256 + tid;
        int row = ch >> 4, cg = ch & 15;
        u16x8 cv = *(const u16x8*)&Cs[row * 136 + cg * 8];
        int m = m0 + pass * 64 + row;
        *(u16x8*)&Cout[(size_t)m * ldc + n0 + cg * 8] = cv;
      }
    } else {
      #pragma unroll
      for (int cc = 0; cc < 4; ++cc) {
        int ch = cc * 256 + tid;
        int row = ch >> 4, cg = ch & 15;
        u16x8 cv = *(const u16x8*)&Cs[row * 136 + cg * 8];
        int c = n0 + pass * 64 + row;
        size_t idx = ((size_t)(b * 256 + c)) * 4096 + nn0 + cg * 8;
        u16x8 sv = *(const u16x8*)&subB[idx];
        float bb = bias[c];
        u16x8 ov;
        #pragma unroll
        for (int e = 0; e < 8; ++e)
          ov[e] = f2bf(bf2f((unsigned short)cv[e]) + bb + bf2f((unsigned short)sv[e]));
        *(u16x8*)&Cout[idx] = ov;
      }
    }
  }
}

// ---------------- kernel 3: dilated local attention ----------------
__global__ __launch_bounds__(256) void k_attn(
    const unsigned short* __restrict__ qkv,   // [NPOS, 768] bf16
    unsigned short* __restrict__ y)           // [NPOS, 256] bf16
{
  int t = threadIdx.x;
  int sub = t >> 2;
  int lane4 = t & 3;
  int item = blockIdx.x * 64 + sub;
  int ih = item & 7;
  int p = item >> 3;
  int i = ih >> 1, h = ih & 1;
  int dil = i + 1;
  int b = p >> 12;
  int n = p & 4095;
  int py = n >> 6, px = n & 63;
  int off = i * 64 + h * 32 + lane4 * 8;
  const unsigned short* base = qkv + off;

  uint4 qw = *(const uint4*)(base + (size_t)p * 768);
  float q0 = blo(qw.x), q1 = bhi(qw.x), q2 = blo(qw.y), q3 = bhi(qw.y),
        q4 = blo(qw.z), q5 = bhi(qw.z), q6 = blo(qw.w), q7 = bhi(qw.w);

  int pj[9];
  #pragma unroll
  for (int j = 0; j < 9; ++j) {
    int ny = py + (j / 3 - 1) * dil;
    int nx = px + (j % 3 - 1) * dil;
    bool ok = ((unsigned)ny < 64u) && ((unsigned)nx < 64u);
    pj[j] = ok ? ((b << 12) + (ny << 6) + nx) : -1;
  }

  float sc[9];
  #pragma unroll
  for (int j = 0; j < 9; ++j) {
    float s = 0.f;
    if (pj[j] >= 0) {
      uint4 kw = *(const uint4*)(base + 256 + (size_t)pj[j] * 768);
      s  = q0 * blo(kw.x) + q1 * bhi(kw.x);
      s += q2 * blo(kw.y) + q3 * bhi(kw.y);
      s += q4 * blo(kw.z) + q5 * bhi(kw.z);
      s += q6 * blo(kw.w) + q7 * bhi(kw.w);
    }
    s += __shfl_xor(s, 1, 4);
    s += __shfl_xor(s, 2, 4);
    sc[j] = s * SCALE_;             // zero-pad taps -> score exactly 0
  }

  float mx = sc[0];
  #pragma unroll
  for (int j = 1; j < 9; ++j) mx = fmaxf(mx, sc[j]);
  float e[9], ssum = 0.f;
  #pragma unroll
  for (int j = 0; j < 9; ++j) { e[j] = __expf(sc[j] - mx); ssum += e[j]; }
  float inv = 1.f / ssum;

  float o0 = 0.f, o1 = 0.f, o2 = 0.f, o3 = 0.f, o4 = 0.f, o5 = 0.f, o6 = 0.f, o7 = 0.f;
  #pragma unroll
  for (int j = 0; j < 9; ++j) {
    if (pj[j] >= 0) {
      float w = e[j] * inv;
      uint4 vw = *(const uint4*)(base + 512 + (size_t)pj[j] * 768);
      o0 += w * blo(vw.x); o1 += w * bhi(vw.x);
      o2 += w * blo(vw.y); o3 += w * bhi(vw.y);
      o4 += w * blo(vw.z); o5 += w * bhi(vw.z);
      o6 += w * blo(vw.w); o7 += w * bhi(vw.w);
    }
  }

  u16x8 ov;
  ov[0] = f2bf(o0); ov[1] = f2bf(o1); ov[2] = f2bf(o2); ov[3] = f2bf(o3);
  ov[4] = f2bf(o4); ov[5] = f2bf(o5); ov[6] = f2bf(o6); ov[7] = f2bf(o7);
  *(u16x8*)(y + (size_t)p * 256 + off) = ov;
}

// ---------------- kernel 5: per-(b,c) 64x64x64 MFMA matmul, dup output ----
// o[i,j] = sum_k vi[i,k] * div[k,j]; A=Vs row-major, B=Ds transposed [j][k].
// Row stride 72 ushorts = 144 B = 9x16B: b128-aligned, conflict-free frags.
__global__ __launch_bounds__(256) void k_bmm(
    const unsigned short* __restrict__ viB,
    const unsigned short* __restrict__ divmB,
    float* __restrict__ out)
{
  __shared__ __align__(16) unsigned short Vs[64 * 72];
  __shared__ __align__(16) unsigned short Ds[64 * 72];
  int bc = blockIdx.x;
  size_t base = (size_t)bc * 4096;
  int t = threadIdx.x;
  {
    int flat = t * 16;
    int row = flat >> 6, col = flat & 63;   // row: i for vi / k for div
    u16x8 v0 = *(const u16x8*)&viB[base + flat];
    u16x8 v1 = *(const u16x8*)&viB[base + flat + 8];
    *(u16x8*)&Vs[row * 72 + col] = v0;
    *(u16x8*)&Vs[row * 72 + col + 8] = v1;
    u16x8 d0 = *(const u16x8*)&divmB[base + flat];
    u16x8 d1 = *(const u16x8*)&divmB[base + flat + 8];
    #pragma unroll
    for (int e = 0; e < 8; ++e) {
      Ds[(col + e) * 72 + row] = (unsigned short)d0[e];       // Ds[j][k]
      Ds[(col + 8 + e) * 72 + row] = (unsigned short)d1[e];
    }
  }
  __syncthreads();
  int w = t >> 6, lane = t & 63;
  int r = lane & 15, q = lane >> 4;
  int wi = (w >> 1) * 32, wj = (w & 1) * 32;
  f32x4 acc[2][2];
  #pragma unroll
  for (int i = 0; i < 2; ++i)
    #pragma unroll
    for (int j = 0; j < 2; ++j)
      acc[i][j] = (f32x4){0.f, 0.f, 0.f, 0.f};
  #pragma unroll
  for (int ks = 0; ks < 2; ++ks) {
    bf16x8 a[2], bfr[2];
    #pragma unroll
    for (int ti = 0; ti < 2; ++ti)
      a[ti] = *(const bf16x8*)&Vs[(wi + ti * 16 + r) * 72 + ks * 32 + q * 8];
    #pragma unroll
    for (int tj = 0; tj < 2; ++tj)
      bfr[tj] = *(const bf16x8*)&Ds[(wj + tj * 16 + r) * 72 + ks * 32 + q * 8];
    #pragma unroll
    for (int ti = 0; ti < 2; ++ti)
      #pragma unroll
      for (int tj = 0; tj < 2; ++tj)
        acc[ti][tj] = __builtin_amdgcn_mfma_f32_16x16x32_bf16(a[ti], bfr[tj], acc[ti][tj], 0, 0, 0);
  }
  #pragma unroll
  for (int ti = 0; ti < 2; ++ti)
    #pragma unroll
    for (int tj = 0; tj < 2; ++tj)
      #pragma unroll
      for (int rr = 0; rr < 4; ++rr) {
        int row = wi + ti * 16 + q * 4 + rr;
        int col = wj + tj * 16 + r;
        float v = acc[ti][tj][rr];
        out[base + row * 64 + col] = v;
        out[8388608ull + base + row * 64 + col] = v;
      }
}

extern "C" void kernel_launch(void* const* d_in, const int* in_sizes, int n_in,
                              void* d_out, int out_size, void* d_ws, size_t ws_size,
                              hipStream_t stream) {
  const float* vi     = (const float*)d_in[0];
  const float* ir     = (const float*)d_in[1];
  const float* w_qkv  = (const float*)d_in[2];
  const float* proj_w = (const float*)d_in[3];
  const float* proj_b = (const float*)d_in[4];
  const float* ln_g   = (const float*)d_in[5];
  const float* ln_b   = (const float*)d_in[6];
  float* out = (float*)d_out;
  char* ws = (char*)d_ws;
  unsigned short* subB = (unsigned short*)(ws);                // 16.8 MB BCHW bf16
  unsigned short* qkvb = (unsigned short*)(ws + 16777216);     // 50.3 MB [NPOS,768]
  unsigned short* divmB= (unsigned short*)(ws + 16777216);     // reuse, 16.8 MB BCHW
  unsigned short* xnb  = (unsigned short*)(ws + 67108864);     // 16.8 MB [NPOS,256]
  unsigned short* yb   = (unsigned short*)(ws + 83886080);     // 16.8 MB [NPOS,256]
  unsigned short* viB  = (unsigned short*)(ws + 100663296);    // 16.8 MB BCHW bf16
  unsigned short* wqb  = (unsigned short*)(ws + 117440512);    // [768,256] bf16
  unsigned short* pwb  = wqb + 196608;                         // [256,256] bf16

  k_pre<<<1280, 256, 0, stream>>>(vi, ir, w_qkv, proj_w, ln_g, ln_b, wqb, subB, viB, xnb);
  k_gemm_mfma<0, 6><<<1536, 256, 0, stream>>>(xnb, wqb, qkvb, nullptr, nullptr, 768);
  k_attn<<<4096, 256, 0, stream>>>(qkvb, yb);
  k_gemm_mfma<1, 2><<<512, 256, 0, stream>>>(yb, pwb, divmB, proj_b, subB, 0);
  k_bmm<<<2048, 256, 0, stream>>>(viB, divmB, out);
}